// Round 7
// baseline (6431.602 us; speedup 1.0000x reference)
//
#include <hip/hip_runtime.h>
#include <hip/hip_bf16.h>

// Problem constants
#define BB 512
#define TT 256
#define SS 64
#define II 32
#define HH 1024
#define K1 96            // S + I
#define KS1 3            // K1/32 (ks=0,1 -> x part; ks=2 -> u part)
#define KS2 32           // H/32

// Packed fragment counts (each fragment = 512 halves = 1KB)
#define W1P_ELEMS (64 * KS1 * 512)   // 98304
#define W2P_ELEMS (64 * KS2 * 512)   // 1048576
#define W3P_ELEMS (4  * KS2 * 512)   // 65536
#define PACK_TOTAL (W1P_ELEMS + W2P_ELEMS + W3P_ELEMS)

// Grid: 256 blocks = 32 batch-groups (16 rows) x 8 H-groups (128 cols).
// 256 threads (4 waves) -> 1 wave/SIMD -> 512 unified regs/wave:
// 256 AGPR (W2 resident) + ~250 VGPR. (Validated R6.)
#define MBG 32
#define NBG 8
#define SLOTBUF (MBG * NBG * 16 * 64)   // floats per parity buffer (1MB)

// d_ws layout (bytes)
#define OFF_W1P   0
#define OFF_W2P   (OFF_W1P + W1P_ELEMS*2)
#define OFF_W3P   (OFF_W2P + W2P_ELEMS*2)
#define OFF_SLOT  (OFF_W3P + W3P_ELEMS*2)        // 2 parity buffers x 1MB
#define OFF_FL    (OFF_SLOT + 2*SLOTBUF*4)

typedef _Float16 f16x8 __attribute__((ext_vector_type(8)));
typedef _Float16 f16x4 __attribute__((ext_vector_type(4)));
typedef float f32x4 __attribute__((ext_vector_type(4)));
typedef unsigned long long u64;

// ---------------------------------------------------------------------------
// Pack fp32 weights -> fp16 fragments in exact MFMA B-operand lane order.
// (validated R1/R3/R4/R6)
// ---------------------------------------------------------------------------
__global__ void pack_weights(const float* __restrict__ W1,
                             const float* __restrict__ W2,
                             const float* __restrict__ W3,
                             _Float16* __restrict__ W1p,
                             _Float16* __restrict__ W2p,
                             _Float16* __restrict__ W3p)
{
    int idx = blockIdx.x * 256 + threadIdx.x;
    if (idx >= PACK_TOTAL) return;
    const float* src;
    _Float16* dst;
    int K, e;
    if (idx < W1P_ELEMS)                 { src = W1; dst = W1p; K = K1; e = idx; }
    else if (idx < W1P_ELEMS + W2P_ELEMS){ src = W2; dst = W2p; K = HH; e = idx - W1P_ELEMS; }
    else                                 { src = W3; dst = W3p; K = HH; e = idx - W1P_ELEMS - W2P_ELEMS; }
    int j    = e & 7;
    int lane = (e >> 3) & 63;
    int f    = e >> 9;
    int KSw  = K / 32;
    int nt   = f / KSw;
    int ks   = f - nt * KSw;
    int n    = nt * 16 + (lane & 15);
    int k    = ks * 32 + ((lane >> 4) << 3) + j;
    dst[e] = (_Float16)src[(size_t)n * K + k];
}

// ---------------------------------------------------------------------------
// LDS helpers — XOR swizzle ^((row&7)<<4): bank-spread for b128 reads.
// ---------------------------------------------------------------------------
__device__ __forceinline__ void st_h16(unsigned char* base, int pitch, int row, int col, _Float16 v) {
    int off = (row * pitch + col * 2) ^ ((row & 7) << 4);
    *(_Float16*)(base + off) = v;
}
__device__ __forceinline__ void st_b64l(unsigned char* base, int pitch, int row, int col, u64 v) {
    int off = (row * pitch + col * 2) ^ ((row & 7) << 4);
    *(u64*)(base + off) = v;
}
__device__ __forceinline__ uint4 ld_b128(const unsigned char* base, int pitch, int row, int col) {
    int off = (row * pitch + col * 2) ^ ((row & 7) << 4);
    return *(const uint4*)(base + off);
}
__device__ __forceinline__ f16x8 ld_frag_lds(const unsigned char* base, int pitch, int row, int k0) {
    return __builtin_bit_cast(f16x8, ld_b128(base, pitch, row, k0));
}
__device__ __forceinline__ f16x8 ldg_frag(const _Float16* __restrict__ p, int fragIdx, int lane) {
    const uint4* q = (const uint4*)(p + (size_t)fragIdx * 512) + lane;
    return __builtin_bit_cast(f16x8, *q);
}
__device__ __forceinline__ float sigmoidf_fast(float z) {
    return 1.0f / (1.0f + __expf(-z));
}
__device__ __forceinline__ u64 pack4h(float a, float b, float c, float d) {
    f16x4 p; p[0]=(_Float16)a; p[1]=(_Float16)b; p[2]=(_Float16)c; p[3]=(_Float16)d;
    return __builtin_bit_cast(u64, p);
}

// Pin a fragment into the AGPR file (unified RF).
#define PIN_AGPR(x) asm("" : "+a"(x))
// MFMA, B operand straight from AGPR (validated R6).
#define MFMA_AV(acc, aFrag, bAgpr) \
    asm("v_mfma_f32_16x16x32_f16 %0, %1, %2, %0" : "+v"(acc) : "v"(aFrag), "a"(bAgpr))
// MFMA, B from VGPR.
#define MFMA_VV(acc, aFrag, bVgpr) \
    asm("v_mfma_f32_16x16x32_f16 %0, %1, %2, %0" : "+v"(acc) : "v"(aFrag), "v"(bVgpr))

// Relaxed agent-scope accesses (sc0sc1, coherent at L3; validated R3/R6).
__device__ __forceinline__ u64 ldg_u64(const u64* p) {
    return __hip_atomic_load((u64*)p, __ATOMIC_RELAXED, __HIP_MEMORY_SCOPE_AGENT);
}
__device__ __forceinline__ void stg_f32(float* p, float v) {
    __hip_atomic_store(p, v, __ATOMIC_RELAXED, __HIP_MEMORY_SCOPE_AGENT);
}
__device__ __forceinline__ int ldg_flag(int* p) {
    return __hip_atomic_load(p, __ATOMIC_RELAXED, __HIP_MEMORY_SCOPE_AGENT);
}
__device__ __forceinline__ void stg_flag(int* p, int v) {
    __hip_atomic_store(p, v, __ATOMIC_RELAXED, __HIP_MEMORY_SCOPE_AGENT);
}
// Bounded spin: deadlock degrades to wrong answer, never a container hang.
__device__ __forceinline__ void spin_ge(int* f, int target, volatile int* dead) {
    if (*dead) return;
    int it = 0;
    while (ldg_flag(f) < target) {
        __builtin_amdgcn_s_sleep(1);
        if (++it > 400000) { *dead = 1; break; }
    }
}

// ---------------------------------------------------------------------------
// Weight-stationary RNN, ONE cross-block sync per step, W2 in AGPRs,
// flag-independent work (u-part of GEMM1 + all W1 streaming) hoisted into
// the spin window.
// Per step:
//   PRE-SYNC : u A-frag from global (no LDS), 16 W1u frags, 16 u-MFMAs into
//              acc[16]; issue 16 W1x (p0) frag loads.
//   SYNC     : tid<8 poll peers' slot flags (t).
//   PHASE A  : gather 8 partial slots -> x_t; write out[t-1]; x -> sXC.
//   GEMM1x   : 32 MFMAs (W1x p0 prefetched, p1 streamed), sigmoid -> sH1A.
//   GEMM2    : K=1024 from sH1A, W2 from AGPRs -> sigmoid -> sH2.
//   GEMM3    : own 128-K partial -> slot store (parity buffer) -> flag.
// Safety invariant (validated R6): flag(s)>=s certifies peer wrote
// slots(s-1) AND finished reading slots(s-2); parity = full-step WAR margin.
// ---------------------------------------------------------------------------
__global__ __launch_bounds__(256, 1) void rnn_main(
    const float* __restrict__ x0, const float* __restrict__ u,
    const float* __restrict__ b1, const float* __restrict__ b2, const float* __restrict__ b3,
    const _Float16* __restrict__ W1p, const _Float16* __restrict__ W2p, const _Float16* __restrict__ W3p,
    float* __restrict__ slots, int* __restrict__ slotflag,
    float* __restrict__ out)
{
    __shared__ __align__(16) unsigned char sH1A[16 * 2048];  // h1 [16][1024] fp16
    __shared__ __align__(16) unsigned char sXC [16 * 128];   // x   [16][64]  fp16
    __shared__ __align__(16) unsigned char sH2 [16 * 256];   // h2  [16][128] fp16
    __shared__ int sDead;

    const int tid  = threadIdx.x;
    const int lane = tid & 63;
    const int w    = tid >> 6;          // wave 0..3
    const int bid  = blockIdx.x;
    const int mb   = bid & 31;
    const int nb   = bid >> 5;
    const int b0   = mb * 16;
    const int col  = lane & 15;
    const int g    = lane >> 4;

    // ---- AGPR-resident W2: own 2 n-tiles x full K (64 frags = 256 AGPR) ----
    const int ntA = nb * 8 + w * 2;
    const int ntB = ntA + 1;
    f16x8 w2f[64];
    #pragma unroll
    for (int ks = 0; ks < KS2; ++ks) {
        w2f[ks] = ldg_frag(W2p, ntA * KS2 + ks, lane);
        PIN_AGPR(w2f[ks]);
    }
    #pragma unroll
    for (int ks = 0; ks < KS2; ++ks) {
        w2f[32 + ks] = ldg_frag(W2p, ntB * KS2 + ks, lane);
        PIN_AGPR(w2f[32 + ks]);
    }

    // Biases. GEMM1: wave owns n-tiles w*16 .. w*16+15.
    float b1v[16];
    #pragma unroll
    for (int j = 0; j < 16; ++j) b1v[j] = b1[(w * 16 + j) * 16 + col];
    const float b2va = b2[ntA * 16 + col];
    const float b2vb = b2[ntB * 16 + col];

    // Gather constants: thread -> (row gm, 4 cols from gs).
    const int gm = tid >> 4;
    const int gs = (tid & 15) * 4;
    float b3v[4];
    #pragma unroll
    for (int i = 0; i < 4; ++i) b3v[i] = b3[gs + i];

    // u A-frag source: lane (col,g) -> batch row b0+col, u cols g*8..g*8+7.
    const float* uBase = u + ((size_t)(b0 + col) * TT) * II + g * 8;

    int* myFL = slotflag + mb * 8;

    if (tid == 0) sDead = 0;
    __syncthreads();

    for (int t = 0;; ++t) {
        f32x4 acc[16];
        if (t < TT) {
            // ---- PRE-SYNC: u-part of GEMM1 (flag-independent) ----
            const float* up = uBase + (size_t)t * II;
            float4 ua = *(const float4*)up;
            float4 ub = *(const float4*)(up + 4);
            f16x8 au;
            au[0]=(_Float16)ua.x; au[1]=(_Float16)ua.y; au[2]=(_Float16)ua.z; au[3]=(_Float16)ua.w;
            au[4]=(_Float16)ub.x; au[5]=(_Float16)ub.y; au[6]=(_Float16)ub.z; au[7]=(_Float16)ub.w;
            #pragma unroll
            for (int i = 0; i < 16; ++i) acc[i] = (f32x4){0.f, 0.f, 0.f, 0.f};
            // 16 W1u frags (ks=2), consumed immediately.
            #pragma unroll
            for (int i = 0; i < 16; ++i) {
                f16x8 wu = ldg_frag(W1p, (w * 16 + i) * KS1 + 2, lane);
                MFMA_VV(acc[i], au, wu);
            }
        }
        // W1x p0 prefetch (i=0..7, ks=0,1) — issued pre-sync, in flight
        // across the spin+gather.
        f16x8 w1xA[8][2];
        if (t < TT) {
            #pragma unroll
            for (int i = 0; i < 8; ++i) {
                w1xA[i][0] = ldg_frag(W1p, (w * 16 + i) * KS1 + 0, lane);
                w1xA[i][1] = ldg_frag(W1p, (w * 16 + i) * KS1 + 1, lane);
            }
        }

        // ---- the ONE sync: peers' slots(t-1) ready? ----
        if (t > 0 && tid < 8) spin_ge(&myFL[tid], t, &sDead);
        __syncthreads();

        // ---- phase A: gather x_t -> sXC (and write out[t-1]) ----
        if (t == 0) {
            const float* xp = x0 + (size_t)(b0 + gm) * SS + gs;
            float4 pa = *(const float4*)xp;
            st_b64l(sXC, 128, gm, gs, pack4h(pa.x, pa.y, pa.z, pa.w));
        } else {
            const float* sb = slots + (size_t)((t - 1) & 1) * SLOTBUF;
            float s0 = b3v[0], s1 = b3v[1], s2 = b3v[2], s3 = b3v[3];
            #pragma unroll
            for (int nb2 = 0; nb2 < 8; ++nb2) {
                const u64* sp = (const u64*)(sb + ((size_t)(mb * 8 + nb2) * 16 + gm) * 64 + gs);
                float2 fa = __builtin_bit_cast(float2, ldg_u64(sp));
                float2 fb = __builtin_bit_cast(float2, ldg_u64(sp + 1));
                s0 += fa.x; s1 += fa.y; s2 += fb.x; s3 += fb.y;
            }
            if (nb == 0) {
                float* op = out + ((size_t)(b0 + gm) * TT + (t - 1)) * SS + gs;
                *(float4*)op = make_float4(s0, s1, s2, s3);
            }
            if (t < TT)
                st_b64l(sXC, 128, gm, gs, pack4h(s0, s1, s2, s3));
        }
        if (t == TT) break;
        __syncthreads();

        // ---- GEMM1x: x-part (ks=0,1), p0 prefetched, p1 streamed ----
        {
            f16x8 af0 = ld_frag_lds(sXC, 128, col, 0 * 32 + g * 8);
            f16x8 af1 = ld_frag_lds(sXC, 128, col, 1 * 32 + g * 8);
            // p1 loads issued first so they overlap p0 MFMAs.
            f16x8 w1xB[8][2];
            #pragma unroll
            for (int i = 0; i < 8; ++i) {
                w1xB[i][0] = ldg_frag(W1p, (w * 16 + 8 + i) * KS1 + 0, lane);
                w1xB[i][1] = ldg_frag(W1p, (w * 16 + 8 + i) * KS1 + 1, lane);
            }
            #pragma unroll
            for (int i = 0; i < 8; ++i) {
                MFMA_VV(acc[i], af0, w1xA[i][0]);
                MFMA_VV(acc[i], af1, w1xA[i][1]);
            }
            asm volatile("s_nop 7\n\ts_nop 7"
                         : "+v"(acc[0]), "+v"(acc[1]), "+v"(acc[2]), "+v"(acc[3]),
                           "+v"(acc[4]), "+v"(acc[5]), "+v"(acc[6]), "+v"(acc[7]));
            #pragma unroll
            for (int i = 0; i < 8; ++i) {
                int n = (w * 16 + i) * 16 + col;
                #pragma unroll
                for (int r = 0; r < 4; ++r)
                    st_h16(sH1A, 2048, g * 4 + r, n,
                           (_Float16)sigmoidf_fast(acc[i][r] + b1v[i]));
            }
            #pragma unroll
            for (int i = 0; i < 8; ++i) {
                MFMA_VV(acc[8 + i], af0, w1xB[i][0]);
                MFMA_VV(acc[8 + i], af1, w1xB[i][1]);
            }
            asm volatile("s_nop 7\n\ts_nop 7"
                         : "+v"(acc[8]), "+v"(acc[9]), "+v"(acc[10]), "+v"(acc[11]),
                           "+v"(acc[12]), "+v"(acc[13]), "+v"(acc[14]), "+v"(acc[15]));
            #pragma unroll
            for (int i = 0; i < 8; ++i) {
                int n = (w * 16 + 8 + i) * 16 + col;
                #pragma unroll
                for (int r = 0; r < 4; ++r)
                    st_h16(sH1A, 2048, g * 4 + r, n,
                           (_Float16)sigmoidf_fast(acc[8 + i][r] + b1v[8 + i]));
            }
        }
        // W3 frags for GEMM3 (L2-hot; latency hidden under GEMM2).
        f16x8 w3f[4];
        #pragma unroll
        for (int ksl = 0; ksl < 4; ++ksl)
            w3f[ksl] = ldg_frag(W3p, w * KS2 + nb * 4 + ksl, lane);
        __syncthreads();

        // ---- GEMM2: 2 n-tiles over K=1024, W2 from AGPRs, 4 acc chains ----
        {
            f32x4 aA0 = (f32x4){0.f,0.f,0.f,0.f}, aA1 = (f32x4){0.f,0.f,0.f,0.f};
            f32x4 aB0 = (f32x4){0.f,0.f,0.f,0.f}, aB1 = (f32x4){0.f,0.f,0.f,0.f};
            #pragma unroll
            for (int ks = 0; ks < KS2; ks += 2) {
                f16x8 a0 = ld_frag_lds(sH1A, 2048, col, ks * 32 + g * 8);
                f16x8 a1 = ld_frag_lds(sH1A, 2048, col, (ks + 1) * 32 + g * 8);
                MFMA_AV(aA0, a0, w2f[ks]);
                MFMA_AV(aB0, a0, w2f[32 + ks]);
                MFMA_AV(aA1, a1, w2f[ks + 1]);
                MFMA_AV(aB1, a1, w2f[32 + ks + 1]);
            }
            asm volatile("s_nop 7\n\ts_nop 7"
                         : "+v"(aA0), "+v"(aA1), "+v"(aB0), "+v"(aB1));
            #pragma unroll
            for (int r = 0; r < 4; ++r) {
                st_h16(sH2, 256, g * 4 + r, (w * 2) * 16 + col,
                       (_Float16)sigmoidf_fast(aA0[r] + aA1[r] + b2va));
                st_h16(sH2, 256, g * 4 + r, (w * 2 + 1) * 16 + col,
                       (_Float16)sigmoidf_fast(aB0[r] + aB1[r] + b2vb));
            }
        }
        __syncthreads();

        // ---- GEMM3 partial (K = own 128 h2 cols): wave w -> S-tile w ----
        {
            f32x4 a3 = (f32x4){0.f, 0.f, 0.f, 0.f};
            #pragma unroll
            for (int ksl = 0; ksl < 4; ++ksl) {
                f16x8 a = ld_frag_lds(sH2, 256, col, ksl * 32 + g * 8);
                MFMA_VV(a3, a, w3f[ksl]);
            }
            asm volatile("s_nop 7\n\ts_nop 7" : "+v"(a3));
            float* sbw = slots + (size_t)(t & 1) * SLOTBUF;
            #pragma unroll
            for (int r = 0; r < 4; ++r)
                stg_f32(&sbw[((size_t)(mb * 8 + nb) * 16 + g * 4 + r) * 64 + w * 16 + col], a3[r]);
        }
        __syncthreads();   // vmcnt(0) drain: slot stores visible at agent scope
        if (tid == 0) stg_flag(&myFL[nb], t + 1);
    }
}

// ---------------------------------------------------------------------------
extern "C" void kernel_launch(void* const* d_in, const int* in_sizes, int n_in,
                              void* d_out, int out_size, void* d_ws, size_t ws_size,
                              hipStream_t stream) {
    const float* x0 = (const float*)d_in[0];
    const float* u  = (const float*)d_in[1];
    const float* W1 = (const float*)d_in[2];
    const float* b1 = (const float*)d_in[3];
    const float* W2 = (const float*)d_in[4];
    const float* b2 = (const float*)d_in[5];
    const float* W3 = (const float*)d_in[6];
    const float* b3 = (const float*)d_in[7];
    float* out = (float*)d_out;

    char* ws = (char*)d_ws;
    _Float16* W1p  = (_Float16*)(ws + OFF_W1P);
    _Float16* W2p  = (_Float16*)(ws + OFF_W2P);
    _Float16* W3p  = (_Float16*)(ws + OFF_W3P);
    float*    slots= (float*)   (ws + OFF_SLOT);
    int*      slfl = (int*)     (ws + OFF_FL);

    hipMemsetAsync(ws + OFF_FL, 0, 1024, stream);
    pack_weights<<<(PACK_TOTAL + 255) / 256, 256, 0, stream>>>(W1, W2, W3, W1p, W2p, W3p);
    rnn_main<<<MBG * NBG, 256, 0, stream>>>(x0, u, b1, b2, b3, W1p, W2p, W3p,
                                            slots, slfl, out);
}

// Round 9
// 2582.000 us; speedup vs baseline: 2.4909x; 2.4909x over previous
//
#include <hip/hip_runtime.h>
#include <hip/hip_bf16.h>

// Problem constants
#define BB 512
#define TT 256
#define SS 64
#define II 32
#define HH 1024
#define K1 96            // S + I
#define KS1 3            // K1/32
#define KS2 32           // H/32

// Packed fragment counts (ELEMENTS, i.e. halves; each fragment = 512 halves
// = 1 KB). W1 packed = 192 fragments = 192 KB total (does NOT fit LDS whole;
// R8's NaN was staging 96 KB and reading 192 KB).
#define W1P_ELEMS (64 * KS1 * 512)   // 98304 halves = 192 KB
#define W2P_ELEMS (64 * KS2 * 512)   // 1048576
#define W3P_ELEMS (4  * KS2 * 512)   // 65536
#define PACK_TOTAL (W1P_ELEMS + W2P_ELEMS + W3P_ELEMS)

// Grid: 256 blocks = 32 batch-groups (16 rows) x 8 H-groups (128 cols).
// 256 threads (4 waves) -> 1 wave/SIMD -> 512 unified regs/wave:
// 256 AGPR (W2 resident) + VGPR working set. (Validated R6; R7 showed any
// extra live-across-sync registers spill -> 6GB scratch FETCH. Keep neutral.)
#define MBG 32
#define NBG 8
#define SLOTBUF (MBG * NBG * 16 * 64)   // floats per parity buffer (1MB)

// d_ws layout (bytes)
#define OFF_W1P   0
#define OFF_W2P   (OFF_W1P + W1P_ELEMS*2)
#define OFF_W3P   (OFF_W2P + W2P_ELEMS*2)
#define OFF_SLOT  (OFF_W3P + W3P_ELEMS*2)        // 2 parity buffers x 1MB
#define OFF_FL    (OFF_SLOT + 2*SLOTBUF*4)

typedef _Float16 f16x8 __attribute__((ext_vector_type(8)));
typedef _Float16 f16x4 __attribute__((ext_vector_type(4)));
typedef float f32x4 __attribute__((ext_vector_type(4)));
typedef unsigned long long u64;

// ---------------------------------------------------------------------------
// Pack fp32 weights -> fp16 fragments in exact MFMA B-operand lane order.
// (validated R1/R3/R4/R6)
// ---------------------------------------------------------------------------
__global__ void pack_weights(const float* __restrict__ W1,
                             const float* __restrict__ W2,
                             const float* __restrict__ W3,
                             _Float16* __restrict__ W1p,
                             _Float16* __restrict__ W2p,
                             _Float16* __restrict__ W3p)
{
    int idx = blockIdx.x * 256 + threadIdx.x;
    if (idx >= PACK_TOTAL) return;
    const float* src;
    _Float16* dst;
    int K, e;
    if (idx < W1P_ELEMS)                 { src = W1; dst = W1p; K = K1; e = idx; }
    else if (idx < W1P_ELEMS + W2P_ELEMS){ src = W2; dst = W2p; K = HH; e = idx - W1P_ELEMS; }
    else                                 { src = W3; dst = W3p; K = HH; e = idx - W1P_ELEMS - W2P_ELEMS; }
    int j    = e & 7;
    int lane = (e >> 3) & 63;
    int f    = e >> 9;
    int KSw  = K / 32;
    int nt   = f / KSw;
    int ks   = f - nt * KSw;
    int n    = nt * 16 + (lane & 15);
    int k    = ks * 32 + ((lane >> 4) << 3) + j;
    dst[e] = (_Float16)src[(size_t)n * K + k];
}

// ---------------------------------------------------------------------------
// LDS helpers — XOR swizzle ^((row&7)<<4): bank-spread for b128 reads.
// ---------------------------------------------------------------------------
__device__ __forceinline__ void st_h16(unsigned char* base, int pitch, int row, int col, _Float16 v) {
    int off = (row * pitch + col * 2) ^ ((row & 7) << 4);
    *(_Float16*)(base + off) = v;
}
__device__ __forceinline__ void st_b64l(unsigned char* base, int pitch, int row, int col, u64 v) {
    int off = (row * pitch + col * 2) ^ ((row & 7) << 4);
    *(u64*)(base + off) = v;
}
__device__ __forceinline__ uint4 ld_b128(const unsigned char* base, int pitch, int row, int col) {
    int off = (row * pitch + col * 2) ^ ((row & 7) << 4);
    return *(const uint4*)(base + off);
}
__device__ __forceinline__ f16x8 ld_frag_lds(const unsigned char* base, int pitch, int row, int k0) {
    return __builtin_bit_cast(f16x8, ld_b128(base, pitch, row, k0));
}
// W1 fragment from LDS cache: frag f at f*1024 + lane*16 (linear; 64 lanes x
// 16B = 1KB contiguous -> 2-way bank aliasing = free).
__device__ __forceinline__ f16x8 ld_frag_w1(const unsigned char* sW1, int fragIdx, int lane) {
    return __builtin_bit_cast(f16x8, *(const uint4*)(sW1 + fragIdx * 1024 + lane * 16));
}
__device__ __forceinline__ f16x8 ldg_frag(const _Float16* __restrict__ p, int fragIdx, int lane) {
    const uint4* q = (const uint4*)(p + (size_t)fragIdx * 512) + lane;
    return __builtin_bit_cast(f16x8, *q);
}
__device__ __forceinline__ float sigmoidf_fast(float z) {
    return 1.0f / (1.0f + __expf(-z));
}
__device__ __forceinline__ u64 pack4h(float a, float b, float c, float d) {
    f16x4 p; p[0]=(_Float16)a; p[1]=(_Float16)b; p[2]=(_Float16)c; p[3]=(_Float16)d;
    return __builtin_bit_cast(u64, p);
}

// Pin a fragment into the AGPR file (unified RF; validated R6).
#define PIN_AGPR(x) asm("" : "+a"(x))
// MFMA, B operand straight from AGPR (validated R6).
#define MFMA_AV(acc, aFrag, bAgpr) \
    asm("v_mfma_f32_16x16x32_f16 %0, %1, %2, %0" : "+v"(acc) : "v"(aFrag), "a"(bAgpr))
// MFMA, B from VGPR.
#define MFMA_VV(acc, aFrag, bVgpr) \
    asm("v_mfma_f32_16x16x32_f16 %0, %1, %2, %0" : "+v"(acc) : "v"(aFrag), "v"(bVgpr))

// Relaxed agent-scope accesses (sc0sc1, coherent at L3; validated R3/R6).
__device__ __forceinline__ u64 ldg_u64(const u64* p) {
    return __hip_atomic_load((u64*)p, __ATOMIC_RELAXED, __HIP_MEMORY_SCOPE_AGENT);
}
__device__ __forceinline__ void stg_f32(float* p, float v) {
    __hip_atomic_store(p, v, __ATOMIC_RELAXED, __HIP_MEMORY_SCOPE_AGENT);
}
__device__ __forceinline__ int ldg_flag(int* p) {
    return __hip_atomic_load(p, __ATOMIC_RELAXED, __HIP_MEMORY_SCOPE_AGENT);
}
__device__ __forceinline__ void stg_flag(int* p, int v) {
    __hip_atomic_store(p, v, __ATOMIC_RELAXED, __HIP_MEMORY_SCOPE_AGENT);
}
// Bounded spin: deadlock degrades to wrong answer, never a container hang.
__device__ __forceinline__ void spin_ge(int* f, int target, volatile int* dead) {
    if (*dead) return;
    int it = 0;
    while (ldg_flag(f) < target) {
        __builtin_amdgcn_s_sleep(1);
        if (++it > 400000) { *dead = 1; break; }
    }
}

// ---------------------------------------------------------------------------
// Weight-stationary RNN, ONE cross-block sync per step.
// = R6 (validated, 2666us) + HALF of W1 (n-tiles 0..31, 96KB) cached in LDS.
// W1 total is 192KB (> 160KB LDS) so the other half (tiles 32..63) streams
// from L2 exactly as in R6, with its 24 loads issued BEFORE the LDS-tile
// MFMAs so the ~600cy L2 latency hides under ~24 ds_read+MFMA. Register
// pressure unchanged-to-lower vs R6 (R7 lesson: stay under the 512 ceiling).
// Per step: [u prestage | spin slots flags] -> gather x -> GEMM1 (8 LDS
// tiles + 8 streamed tiles per wave) -> GEMM2 (W2 from AGPRs) -> GEMM3
// partial -> slot store (parity) -> flag.
// Safety: flag(s)>=s certifies peer wrote slots(s-1) AND finished reading
// slots(s-2); parity buffers give a full-step WAR margin.
// ---------------------------------------------------------------------------
__global__ __launch_bounds__(256, 1) void rnn_main(
    const float* __restrict__ x0, const float* __restrict__ u,
    const float* __restrict__ b1, const float* __restrict__ b2, const float* __restrict__ b3,
    const _Float16* __restrict__ W1p, const _Float16* __restrict__ W2p, const _Float16* __restrict__ W3p,
    float* __restrict__ slots, int* __restrict__ slotflag,
    float* __restrict__ out)
{
    __shared__ __align__(16) unsigned char sW1 [96 * 1024];  // W1 tiles 0..31 (96 frags)
    __shared__ __align__(16) unsigned char sH1A[16 * 2048];  // h1 [16][1024] fp16
    __shared__ __align__(16) unsigned char sXC [16 * 256];   // xcat [16][128] fp16
    __shared__ __align__(16) unsigned char sH2 [16 * 256];   // h2 [16][128] fp16
    __shared__ int sDead;

    const int tid  = threadIdx.x;
    const int lane = tid & 63;
    const int w    = tid >> 6;          // wave 0..3
    const int bid  = blockIdx.x;
    const int mb   = bid & 31;
    const int nb   = bid >> 5;
    const int b0   = mb * 16;
    const int col  = lane & 15;
    const int g    = lane >> 4;

    // ---- AGPR-resident W2: own 2 n-tiles x full K (64 frags = 256 AGPR) ----
    const int ntA = nb * 8 + w * 2;
    const int ntB = ntA + 1;
    f16x8 w2f[64];
    #pragma unroll
    for (int ks = 0; ks < KS2; ++ks) {
        w2f[ks] = ldg_frag(W2p, ntA * KS2 + ks, lane);
        PIN_AGPR(w2f[ks]);
    }
    #pragma unroll
    for (int ks = 0; ks < KS2; ++ks) {
        w2f[32 + ks] = ldg_frag(W2p, ntB * KS2 + ks, lane);
        PIN_AGPR(w2f[32 + ks]);
    }

    // ---- Stage W1 first half into LDS once (fragments 0..95 = 96KB) ----
    {
        const uint4* src = (const uint4*)W1p;   // first 6144 uint4 = 96KB
        uint4* dst = (uint4*)sW1;
        for (int i = tid; i < 6144; i += 256) dst[i] = src[i];
    }

    // Biases. GEMM1: wave owns LDS tiles w*8+i and stream tiles 32+w*8+i.
    float b1v[16];
    #pragma unroll
    for (int i = 0; i < 8; ++i) {
        b1v[i]     = b1[(w * 8 + i) * 16 + col];
        b1v[8 + i] = b1[(32 + w * 8 + i) * 16 + col];
    }
    const float b2va = b2[ntA * 16 + col];
    const float b2vb = b2[ntB * 16 + col];

    // Gather constants: thread -> (row gm, 4 cols from gs).
    const int gm = tid >> 4;
    const int gs = (tid & 15) * 4;
    float b3v[4];
    #pragma unroll
    for (int i = 0; i < 4; ++i) b3v[i] = b3[gs + i];

    int* myFL = slotflag + mb * 8;

    if (tid == 0) sDead = 0;
    __syncthreads();

    for (int t = 0;; ++t) {
        // ---- u_t prestage (independent of flags; overlaps the spin) ----
        if (t < TT && tid >= 128) {
            int tr = tid - 128;
            int m = tr >> 3, i4 = tr & 7;
            const float* up = u + ((size_t)(b0 + m) * TT + t) * II + i4 * 4;
            float4 uv = *(const float4*)up;
            st_b64l(sXC, 256, m, 64 + i4 * 4, pack4h(uv.x, uv.y, uv.z, uv.w));
        }
        // ---- the ONE sync: peers' slots(t-1) ready? ----
        if (t > 0 && tid < 8) spin_ge(&myFL[tid], t, &sDead);
        __syncthreads();

        // ---- gather x_t -> sXC cols 0..63 (and write out[t-1]) ----
        if (t == 0) {
            const float* xp = x0 + (size_t)(b0 + gm) * SS + gs;
            float4 pa = *(const float4*)xp;
            st_b64l(sXC, 256, gm, gs, pack4h(pa.x, pa.y, pa.z, pa.w));
        } else {
            const float* sb = slots + (size_t)((t - 1) & 1) * SLOTBUF;
            float s0 = b3v[0], s1 = b3v[1], s2 = b3v[2], s3 = b3v[3];
            #pragma unroll
            for (int nb2 = 0; nb2 < 8; ++nb2) {
                const u64* sp = (const u64*)(sb + ((size_t)(mb * 8 + nb2) * 16 + gm) * 64 + gs);
                float2 fa = __builtin_bit_cast(float2, ldg_u64(sp));
                float2 fb = __builtin_bit_cast(float2, ldg_u64(sp + 1));
                s0 += fa.x; s1 += fa.y; s2 += fb.x; s3 += fb.y;
            }
            if (nb == 0) {
                float* op = out + ((size_t)(b0 + gm) * TT + (t - 1)) * SS + gs;
                *(float4*)op = make_float4(s0, s1, s2, s3);
            }
            if (t < TT)
                st_b64l(sXC, 256, gm, gs, pack4h(s0, s1, s2, s3));
        }
        if (t == TT) break;
        __syncthreads();

        // ---- GEMM1 (FULL h1, replicated): 8 LDS tiles + 8 streamed tiles --
        {
            f16x8 af[KS1];
            #pragma unroll
            for (int ks = 0; ks < KS1; ++ks)
                af[ks] = ld_frag_lds(sXC, 256, col, ks * 32 + g * 8);

            // Stream-pass loads issued first: latency hides under LDS pass.
            f16x8 wf[8][KS1];
            #pragma unroll
            for (int i = 0; i < 8; ++i)
                #pragma unroll
                for (int ks = 0; ks < KS1; ++ks)
                    wf[i][ks] = ldg_frag(W1p, (32 + w * 8 + i) * KS1 + ks, lane);

            // LDS pass: tiles w*8+i from sW1.
            {
                f32x4 acc[8];
                #pragma unroll
                for (int i = 0; i < 8; ++i) acc[i] = (f32x4){0.f, 0.f, 0.f, 0.f};
                #pragma unroll
                for (int i = 0; i < 8; ++i) {
                    const int f0 = (w * 8 + i) * KS1;
                    #pragma unroll
                    for (int ks = 0; ks < KS1; ++ks) {
                        f16x8 wl = ld_frag_w1(sW1, f0 + ks, lane);
                        MFMA_VV(acc[i], af[ks], wl);
                    }
                }
                asm volatile("s_nop 7\n\ts_nop 7"
                             : "+v"(acc[0]), "+v"(acc[1]), "+v"(acc[2]), "+v"(acc[3]),
                               "+v"(acc[4]), "+v"(acc[5]), "+v"(acc[6]), "+v"(acc[7]));
                #pragma unroll
                for (int i = 0; i < 8; ++i) {
                    int n = (w * 8 + i) * 16 + col;
                    #pragma unroll
                    for (int r = 0; r < 4; ++r)
                        st_h16(sH1A, 2048, g * 4 + r, n,
                               (_Float16)sigmoidf_fast(acc[i][r] + b1v[i]));
                }
            }
            // Stream pass: tiles 32+w*8+i from registers (loads long issued).
            {
                f32x4 acc[8];
                #pragma unroll
                for (int i = 0; i < 8; ++i) acc[i] = (f32x4){0.f, 0.f, 0.f, 0.f};
                #pragma unroll
                for (int i = 0; i < 8; ++i)
                    #pragma unroll
                    for (int ks = 0; ks < KS1; ++ks)
                        MFMA_VV(acc[i], af[ks], wf[i][ks]);
                asm volatile("s_nop 7\n\ts_nop 7"
                             : "+v"(acc[0]), "+v"(acc[1]), "+v"(acc[2]), "+v"(acc[3]),
                               "+v"(acc[4]), "+v"(acc[5]), "+v"(acc[6]), "+v"(acc[7]));
                #pragma unroll
                for (int i = 0; i < 8; ++i) {
                    int n = (32 + w * 8 + i) * 16 + col;
                    #pragma unroll
                    for (int r = 0; r < 4; ++r)
                        st_h16(sH1A, 2048, g * 4 + r, n,
                               (_Float16)sigmoidf_fast(acc[i][r] + b1v[8 + i]));
                }
            }
        }
        // W3 frags for GEMM3 (L2-hot; latency hidden under GEMM2).
        f16x8 w3f[4];
        #pragma unroll
        for (int ksl = 0; ksl < 4; ++ksl)
            w3f[ksl] = ldg_frag(W3p, w * KS2 + nb * 4 + ksl, lane);
        __syncthreads();

        // ---- GEMM2: 2 n-tiles over K=1024, W2 from AGPRs, 4 acc chains ----
        {
            f32x4 aA0 = (f32x4){0.f,0.f,0.f,0.f}, aA1 = (f32x4){0.f,0.f,0.f,0.f};
            f32x4 aB0 = (f32x4){0.f,0.f,0.f,0.f}, aB1 = (f32x4){0.f,0.f,0.f,0.f};
            #pragma unroll
            for (int ks = 0; ks < KS2; ks += 2) {
                f16x8 a0 = ld_frag_lds(sH1A, 2048, col, ks * 32 + g * 8);
                f16x8 a1 = ld_frag_lds(sH1A, 2048, col, (ks + 1) * 32 + g * 8);
                MFMA_AV(aA0, a0, w2f[ks]);
                MFMA_AV(aB0, a0, w2f[32 + ks]);
                MFMA_AV(aA1, a1, w2f[ks + 1]);
                MFMA_AV(aB1, a1, w2f[32 + ks + 1]);
            }
            asm volatile("s_nop 7\n\ts_nop 7"
                         : "+v"(aA0), "+v"(aA1), "+v"(aB0), "+v"(aB1));
            #pragma unroll
            for (int r = 0; r < 4; ++r) {
                st_h16(sH2, 256, g * 4 + r, (w * 2) * 16 + col,
                       (_Float16)sigmoidf_fast(aA0[r] + aA1[r] + b2va));
                st_h16(sH2, 256, g * 4 + r, (w * 2 + 1) * 16 + col,
                       (_Float16)sigmoidf_fast(aB0[r] + aB1[r] + b2vb));
            }
        }
        __syncthreads();

        // ---- GEMM3 partial (K = own 128 h2 cols): wave w -> S-tile w ----
        {
            f32x4 a3 = (f32x4){0.f, 0.f, 0.f, 0.f};
            #pragma unroll
            for (int ksl = 0; ksl < 4; ++ksl) {
                f16x8 a = ld_frag_lds(sH2, 256, col, ksl * 32 + g * 8);
                MFMA_VV(a3, a, w3f[ksl]);
            }
            asm volatile("s_nop 7\n\ts_nop 7" : "+v"(a3));
            float* sbw = slots + (size_t)(t & 1) * SLOTBUF;
            #pragma unroll
            for (int r = 0; r < 4; ++r)
                stg_f32(&sbw[((size_t)(mb * 8 + nb) * 16 + g * 4 + r) * 64 + w * 16 + col], a3[r]);
        }
        __syncthreads();   // vmcnt(0) drain: slot stores visible at agent scope
        if (tid == 0) stg_flag(&myFL[nb], t + 1);
    }
}

// ---------------------------------------------------------------------------
extern "C" void kernel_launch(void* const* d_in, const int* in_sizes, int n_in,
                              void* d_out, int out_size, void* d_ws, size_t ws_size,
                              hipStream_t stream) {
    const float* x0 = (const float*)d_in[0];
    const float* u  = (const float*)d_in[1];
    const float* W1 = (const float*)d_in[2];
    const float* b1 = (const float*)d_in[3];
    const float* W2 = (const float*)d_in[4];
    const float* b2 = (const float*)d_in[5];
    const float* W3 = (const float*)d_in[6];
    const float* b3 = (const float*)d_in[7];
    float* out = (float*)d_out;

    char* ws = (char*)d_ws;
    _Float16* W1p  = (_Float16*)(ws + OFF_W1P);
    _Float16* W2p  = (_Float16*)(ws + OFF_W2P);
    _Float16* W3p  = (_Float16*)(ws + OFF_W3P);
    float*    slots= (float*)   (ws + OFF_SLOT);
    int*      slfl = (int*)     (ws + OFF_FL);

    hipMemsetAsync(ws + OFF_FL, 0, 1024, stream);
    pack_weights<<<(PACK_TOTAL + 255) / 256, 256, 0, stream>>>(W1, W2, W3, W1p, W2p, W3p);
    rnn_main<<<MBG * NBG, 256, 0, stream>>>(x0, u, b1, b2, b3, W1p, W2p, W3p,
                                            slots, slfl, out);
}